// Round 6
// baseline (265.551 us; speedup 1.0000x reference)
//
#include <hip/hip_runtime.h>
#include <math.h>

#define CCH 512
#define NH 4
#define HD 128
#define HW 1024
#define BATCH 16
#define EPS 1e-5f

typedef __attribute__((ext_vector_type(8))) short bfrag;    // 8 bf16 = 4 VGPRs
typedef __attribute__((ext_vector_type(4))) float f4;
typedef __attribute__((ext_vector_type(16))) float f16v;    // 32x32 accum

static __device__ __forceinline__ unsigned short f2bf(float f) {
  union { float f; unsigned u; } v;
  v.f = f;
  unsigned r = v.u + 0x7fff + ((v.u >> 16) & 1);  // RNE
  return (unsigned short)(r >> 16);
}
// packed f32x2 -> bf16x2 in one VALU op (gfx950). src0 -> low half.
static __device__ __forceinline__ unsigned cvt_pk_bf16(float a, float b) {
  unsigned r;
  asm("v_cvt_pk_bf16_f32 %0, %1, %2" : "=v"(r) : "v"(a), "v"(b));
  return r;
}
// exp2 via HW transcendental (no log2e multiply; folded into Q scale)
#if defined(__has_builtin) && __has_builtin(__builtin_amdgcn_exp2f)
#define EXP2(x) __builtin_amdgcn_exp2f(x)
#else
#define EXP2(x) __expf((x) * 0.6931471805599453f)  // e^(x ln2) == 2^x
#endif
// async global->LDS, 16B/lane. LDS dest = wave-uniform base + lane*16.
static __device__ __forceinline__ void ldg_lds16(const unsigned short* g,
                                                 unsigned short* l) {
  __builtin_amdgcn_global_load_lds(
      (const __attribute__((address_space(1))) unsigned int*)g,
      (__attribute__((address_space(3))) unsigned int*)l, 16, 0, 0);
}

// softmax scale folded into Q GEMM epilogue. Includes log2(e) so the
// attention softmax can use raw v_exp_f32 (2^x): 2^(s*log2e) == e^s exactly.
#define QSCALE (0.08838834764831845f * 1.4426950408889634f)

// main-loop LDS swizzle: rows r,r+4 no longer alias -> 2-way banks
#define SWZ(r) (((r) ^ ((r) >> 2)) & 3)

// ---------- fused: GroupNorm (blocks 0..511) + weight cvt (512..1535) -----
__global__ __launch_bounds__(256) void gnw_kernel(
    const float* __restrict__ x, const float* __restrict__ gamma,
    const float* __restrict__ beta, unsigned short* __restrict__ hn,
    const float* __restrict__ wq, const float* __restrict__ wk,
    const float* __restrict__ wv, const float* __restrict__ wp,
    unsigned short* __restrict__ wB) {
  int bx = blockIdx.x;
  int t = threadIdx.x;
  if (bx >= 512) {  // ---- weight fp32 -> bf16 ----
    int i0 = bx - 512;
    int mat = i0 >> 8;
    const float* srcs[4] = {wq, wk, wv, wp};
    const float* s = srcs[mat];
    unsigned short* dp = wB + (size_t)mat * CCH * CCH;
    int i = (i0 & 255) * 256 + t;
    f4 v = ((const f4*)s)[i];
    uint2 o;
    o.x = cvt_pk_bf16(v.x, v.y);
    o.y = cvt_pk_bf16(v.z, v.w);
    *(uint2*)&((ushort4*)dp)[i] = o;
    return;
  }
  // ---- GroupNorm -> position-major bf16 hn_t[b][hw][c] ----
  int b = bx >> 5, g = bx & 31;
  const float* xp = x + ((size_t)b * CCH + g * 16) * HW;
  float s = 0.f, ss = 0.f;
  const f4* xp4 = (const f4*)xp;
  f4 vv[16];
#pragma unroll
  for (int c = 0; c < 16; ++c) {
    f4 v = xp4[c * 256 + t];  // channel c, positions 4t..4t+3
    vv[c] = v;
    s += v.x + v.y + v.z + v.w;
    ss += v.x * v.x + v.y * v.y + v.z * v.z + v.w * v.w;
  }
#pragma unroll
  for (int off = 32; off > 0; off >>= 1) {
    s += __shfl_xor(s, off);
    ss += __shfl_xor(ss, off);
  }
  __shared__ float rs[4], rss[4];
  int w = t >> 6;
  if ((t & 63) == 0) { rs[w] = s; rss[w] = ss; }
  __syncthreads();
  s = rs[0] + rs[1] + rs[2] + rs[3];
  ss = rss[0] + rss[1] + rss[2] + rss[3];
  const float invn = 1.f / (16 * HW);
  float mean = s * invn;
  float var = ss * invn - mean * mean;
  float rstd = rsqrtf(var + EPS);
  float a_[16], b_[16];
#pragma unroll
  for (int c = 0; c < 16; ++c) {
    float gm = gamma[g * 16 + c] * rstd;
    a_[c] = gm;
    b_[c] = beta[g * 16 + c] - mean * gm;
  }
#pragma unroll
  for (int i = 0; i < 4; ++i) {
    int p = 4 * t + i;
    uint4 u0, u1;
    u0.x = cvt_pk_bf16(vv[0][i] * a_[0] + b_[0], vv[1][i] * a_[1] + b_[1]);
    u0.y = cvt_pk_bf16(vv[2][i] * a_[2] + b_[2], vv[3][i] * a_[3] + b_[3]);
    u0.z = cvt_pk_bf16(vv[4][i] * a_[4] + b_[4], vv[5][i] * a_[5] + b_[5]);
    u0.w = cvt_pk_bf16(vv[6][i] * a_[6] + b_[6], vv[7][i] * a_[7] + b_[7]);
    u1.x = cvt_pk_bf16(vv[8][i] * a_[8] + b_[8], vv[9][i] * a_[9] + b_[9]);
    u1.y = cvt_pk_bf16(vv[10][i] * a_[10] + b_[10], vv[11][i] * a_[11] + b_[11]);
    u1.z = cvt_pk_bf16(vv[12][i] * a_[12] + b_[12], vv[13][i] * a_[13] + b_[13]);
    u1.w = cvt_pk_bf16(vv[14][i] * a_[14] + b_[14], vv[15][i] * a_[15] + b_[15]);
    unsigned short* dst = hn + ((size_t)b * HW + p) * CCH + g * 16;
    *(uint4*)dst = u0;
    *(uint4*)(dst + 8) = u1;
  }
}

// ---------- fused QKV GEMM: 3-buffer 2-deep pipeline (counted vmcnt) ------
// D = Xt[b] @ W^T + bias, 128x128 block, K=512 (16 steps of 32).
// blockIdx.y < 8 : Q,K (mats 0/1): SWAPPED operands -> D[m=ch][n=pos] ->
//                  LDS-transpose epilogue -> pos-major rows (full lines).
// blockIdx.y >= 8: V (mat 2): normal -> ch-major bf16 (8B quads).
// Pipeline per iter: vmcnt(4) [tile k retired, k+1 in flight] -> raw
// s_barrier -> sched_barrier -> stage(k+2) -> ds_read+MFMA. Stage-to-use
// distance = 2 iters (>=500cy) so L2/HBM latency is fully hidden; the
// barrier never drains the in-flight prefetch (T4).
// LDS: 3 bufs x 16KB = 48KB -> 3 blocks/CU.
__global__ __launch_bounds__(256, 3) void qkv_kernel(
    const unsigned short* __restrict__ Xt, const unsigned short* __restrict__ Wb,
    const float* __restrict__ bq, const float* __restrict__ bk,
    const float* __restrict__ bv, unsigned short* __restrict__ Qt,
    unsigned short* __restrict__ Kt, unsigned short* __restrict__ Vc) {
  int b = blockIdx.z;
  int p0 = blockIdx.x * 128;
  bool vpath = blockIdx.y >= 8;
  int c0g = (vpath ? blockIdx.y - 8 : blockIdx.y) * 128;
  __shared__ __align__(16) unsigned short S_[24576];  // 48KB = 3 x (X8K|W8K)
  int t = threadIdx.x;
  int w = t >> 6, lane = t & 63, l15 = lane & 15, quad = lane >> 4;
  int wp = (w & 1) * 64, wc = (w >> 1) * 64;
  const unsigned short* Xb = Xt + (size_t)b * HW * CCH;
  const unsigned short* Wr = Wb + (vpath ? (size_t)2 * CCH * CCH : 0) +
                             (size_t)c0g * CCH;
  f4 acc[4][4] = {};
  auto stage = [&](int k0, int bi) {
    unsigned short* Xd = S_ + bi * 8192;
    unsigned short* Wd = Xd + 4096;
#pragma unroll
    for (int j = 0; j < 2; ++j) {
      int chk = w * 2 + j;             // 1KB chunk = 16 rows x 64B
      int r = chk * 16 + (lane >> 2);
      int c = (lane & 3) ^ SWZ(r);     // XOR swizzle (bank-spread)
      ldg_lds16(&Xb[(size_t)(p0 + r) * CCH + k0 + c * 8], Xd + chk * 512);
      ldg_lds16(&Wr[(size_t)r * CCH + k0 + c * 8], Wd + chk * 512);
    }
  };
  stage(0, 0);
  stage(32, 1);
  int cur = 0;
  for (int k0 = 0; k0 < CCH; k0 += 32) {
    if (k0 < CCH - 32)
      asm volatile("s_waitcnt vmcnt(4)" ::: "memory");  // tile k done, k+1 fly
    else
      asm volatile("s_waitcnt vmcnt(0)" ::: "memory");
    __builtin_amdgcn_s_barrier();
    __builtin_amdgcn_sched_barrier(0);
    if (k0 + 64 < CCH) stage(k0 + 64, cur ? cur - 1 : 2);  // buf (cur+2)%3
    const unsigned short* Xc = S_ + cur * 8192;
    const unsigned short* Wc = Xc + 4096;
    bfrag af[4], bf[4];
#pragma unroll
    for (int pt = 0; pt < 4; ++pt) {
      int r = wp + pt * 16 + l15;
      af[pt] = *(const bfrag*)&Xc[r * 32 + ((quad ^ SWZ(r)) << 3)];
    }
#pragma unroll
    for (int ct = 0; ct < 4; ++ct) {
      int r = wc + ct * 16 + l15;
      bf[ct] = *(const bfrag*)&Wc[r * 32 + ((quad ^ SWZ(r)) << 3)];
    }
    if (!vpath) {  // swapped: D[m=ch][n=pos]
#pragma unroll
      for (int pt = 0; pt < 4; ++pt)
#pragma unroll
        for (int ct = 0; ct < 4; ++ct)
          acc[pt][ct] = __builtin_amdgcn_mfma_f32_16x16x32_bf16(
              bf[ct], af[pt], acc[pt][ct], 0, 0, 0);
    } else {
#pragma unroll
      for (int pt = 0; pt < 4; ++pt)
#pragma unroll
        for (int ct = 0; ct < 4; ++ct)
          acc[pt][ct] = __builtin_amdgcn_mfma_f32_16x16x32_bf16(
              af[pt], bf[ct], acc[pt][ct], 0, 0, 0);
    }
    cur = cur == 2 ? 0 : cur + 1;
  }
  if (!vpath) {
    // acc[pt][ct]: ch = wc+ct*16+quad*4+i, pos = wp+pt*16+l15
    int mat = c0g >> 9;
    int c0 = c0g & 511;
    const float* bias = mat ? bk : bq;
    unsigned short* O = mat ? Kt : Qt;
    const float sc = mat ? 1.0f : QSCALE;
    __syncthreads();  // all waves done with k-loop LDS before reuse
    // LDS transpose buffer: [pos 128][ch 128] bf16 = 32KB (reuses S_).
    // 8B-granule XOR swizzle: granule g at row pos stored at g ^ ((pos&7)<<1)
#pragma unroll
    for (int ct = 0; ct < 4; ++ct) {
      f4 bi = *(const f4*)&bias[c0 + wc + ct * 16 + quad * 4];
      int g = (wc >> 2) + ct * 4 + quad;  // 8B granule index (0..31)
#pragma unroll
      for (int pt = 0; pt < 4; ++pt) {
        int pos = wp + pt * 16 + l15;
        f4 v = acc[pt][ct];
        uint2 d;
        d.x = cvt_pk_bf16((v.x + bi.x) * sc, (v.y + bi.y) * sc);
        d.y = cvt_pk_bf16((v.z + bi.z) * sc, (v.w + bi.w) * sc);
        int gs = g ^ ((pos & 7) << 1);
        *(uint2*)&S_[pos * 128 + gs * 4] = d;
      }
    }
    __syncthreads();
    unsigned short* Op = O + (size_t)b * HW * CCH;
#pragma unroll
    for (int it = 0; it < 8; ++it) {
      int row = w * 32 + it * 4 + (lane >> 4);   // wave w owns rows w*32..+31
      int g0 = (2 * l15) ^ ((row & 7) << 1);     // 16B granule (even ^ even)
      uint4 val = *(const uint4*)&S_[row * 128 + g0 * 4];
      *(uint4*)&Op[(size_t)(p0 + row) * CCH + c0 + l15 * 8] = val;
    }
  } else {
    // normal: pos = p0+wp+pt*16+quad*4+i, ch = c0g+wc+ct*16+l15 (V ch-major)
#pragma unroll
    for (int ct = 0; ct < 4; ++ct) {
      int ch = c0g + wc + ct * 16 + l15;
      float bi = bv[ch];
      unsigned short* Op = Vc + (size_t)b * CCH * HW;
#pragma unroll
      for (int pt = 0; pt < 4; ++pt) {
        int pos = p0 + wp + pt * 16 + quad * 4;
        f4 v = acc[pt][ct];
        uint2 st;
        st.x = cvt_pk_bf16(v.x + bi, v.y + bi);
        st.y = cvt_pk_bf16(v.z + bi, v.w + bi);
        *(uint2*)&Op[(size_t)ch * HW + pos] = st;
      }
    }
  }
}

// ---------- P-projection GEMM (same 3-buffer pipeline) + residual ---------
__global__ __launch_bounds__(256, 3) void mmp_kernel(
    const unsigned short* __restrict__ Xt, const unsigned short* __restrict__ Wb,
    const float* __restrict__ b0, const float* __restrict__ resid,
    float* __restrict__ Ofp) {
  int b = blockIdx.z;
  int p0 = blockIdx.x * 128;
  int c0g = blockIdx.y * 128;
  __shared__ __align__(16) unsigned short S_[24576];  // 48KB
  int t = threadIdx.x;
  int w = t >> 6, lane = t & 63, l15 = lane & 15, quad = lane >> 4;
  int wp = (w & 1) * 64, wc = (w >> 1) * 64;
  const unsigned short* Xb = Xt + (size_t)b * HW * CCH;
  const unsigned short* Wr = Wb + (size_t)c0g * CCH;
  f4 acc[4][4] = {};
  auto stage = [&](int k0, int bi) {
    unsigned short* Xd = S_ + bi * 8192;
    unsigned short* Wd = Xd + 4096;
#pragma unroll
    for (int j = 0; j < 2; ++j) {
      int chk = w * 2 + j;
      int r = chk * 16 + (lane >> 2);
      int c = (lane & 3) ^ SWZ(r);
      ldg_lds16(&Xb[(size_t)(p0 + r) * CCH + k0 + c * 8], Xd + chk * 512);
      ldg_lds16(&Wr[(size_t)r * CCH + k0 + c * 8], Wd + chk * 512);
    }
  };
  stage(0, 0);
  stage(32, 1);
  int cur = 0;
  for (int k0 = 0; k0 < CCH; k0 += 32) {
    if (k0 < CCH - 32)
      asm volatile("s_waitcnt vmcnt(4)" ::: "memory");
    else
      asm volatile("s_waitcnt vmcnt(0)" ::: "memory");
    __builtin_amdgcn_s_barrier();
    __builtin_amdgcn_sched_barrier(0);
    if (k0 + 64 < CCH) stage(k0 + 64, cur ? cur - 1 : 2);
    const unsigned short* Xc = S_ + cur * 8192;
    const unsigned short* Wc = Xc + 4096;
    bfrag af[4], bf[4];
#pragma unroll
    for (int pt = 0; pt < 4; ++pt) {
      int r = wp + pt * 16 + l15;
      af[pt] = *(const bfrag*)&Xc[r * 32 + ((quad ^ SWZ(r)) << 3)];
    }
#pragma unroll
    for (int ct = 0; ct < 4; ++ct) {
      int r = wc + ct * 16 + l15;
      bf[ct] = *(const bfrag*)&Wc[r * 32 + ((quad ^ SWZ(r)) << 3)];
    }
#pragma unroll
    for (int pt = 0; pt < 4; ++pt)
#pragma unroll
      for (int ct = 0; ct < 4; ++ct)
        acc[pt][ct] = __builtin_amdgcn_mfma_f32_16x16x32_bf16(
            af[pt], bf[ct], acc[pt][ct], 0, 0, 0);
    cur = cur == 2 ? 0 : cur + 1;
  }
#pragma unroll
  for (int ct = 0; ct < 4; ++ct) {
    int ch = c0g + wc + ct * 16 + l15;
    float bi = b0[ch];
#pragma unroll
    for (int pt = 0; pt < 4; ++pt) {
      int pos = p0 + wp + pt * 16 + quad * 4;
      f4 v = acc[pt][ct];
      size_t off = (size_t)b * CCH * HW + (size_t)ch * HW + pos;
      float4 rv = *(const float4*)&resid[off];
      float4 st;
      st.x = v.x + bi + rv.x; st.y = v.y + bi + rv.y;
      st.z = v.z + bi + rv.z; st.w = v.w + bi + rv.w;
      *(float4*)&Ofp[off] = st;
    }
  }
}

// ---------- Flash attention: frozen at round-5 banked best (~46.4us) ------
__global__ __launch_bounds__(256, 2) void attn_kernel(
    const unsigned short* __restrict__ Qt, const unsigned short* __restrict__ Kt,
    const unsigned short* __restrict__ Vc, unsigned short* __restrict__ Ot) {
  int bh = blockIdx.x;
  int b = bh >> 2, h = bh & 3;
  int q0 = blockIdx.y * 128;
  int t = threadIdx.x;
  int w = t >> 6, lane = t & 63;
  int l31 = lane & 31, half = lane >> 5;
  __shared__ __align__(16) unsigned short Ks[2][64 * 128];  // 2 x 16KB
  __shared__ __align__(16) unsigned short Vs[2][128 * 64];  // 2 x 16KB
  int q = q0 + w * 32 + l31;  // this lane's query
  const unsigned short* Kbase = Kt + (size_t)b * HW * CCH + h * HD;
  const unsigned short* Vbase = Vc + ((size_t)b * CCH + h * HD) * HW;
  // Q B-frags: B[k=ks*16+half*8+j][n=q], loop-invariant
  bfrag qf[8];
#pragma unroll
  for (int ks = 0; ks < 8; ++ks)
    qf[ks] = *(const bfrag*)&Qt[((size_t)b * HW + q) * CCH + h * HD +
                                ks * 16 + half * 8];
  f16v o[4] = {};   // PV accum: D[m=d (4x32)][n=q]
  float ls[4] = {}; // rotating partial row-sums (short dep chains)
  // staging: wave w owns chunks 4w..4w+3 of Ks and of Vs (1KB each)
  auto stage = [&](int kt, int bi) {
    int kk0 = kt * 64;
#pragma unroll
    for (int j = 0; j < 4; ++j) {
      int chk = w * 4 + j;
      {  // Ks chunk: 4 rows x 256B
        int r = chk * 4 + (lane >> 4);
        int c = (lane & 15) ^ (r & 15);
        ldg_lds16(&Kbase[(size_t)(kk0 + r) * CCH + c * 8], &Ks[bi][chk * 512]);
      }
      {  // Vs chunk: 8 rows x 128B
        int r = chk * 8 + (lane >> 3);
        int c = (lane & 7) ^ (r & 7);
        ldg_lds16(&Vbase[(size_t)r * HW + kk0 + c * 8], &Vs[bi][chk * 512]);
      }
    }
  };
  stage(0, 0);
  for (int kt = 0; kt < 16; ++kt) {
    __syncthreads();  // stage(kt) complete everywhere; prev-iter reads done
    if (kt < 15) stage(kt + 1, (kt + 1) & 1);  // overlaps compute below
    const unsigned short* K_ = Ks[kt & 1];
    const unsigned short* V_ = Vs[kt & 1];
    // QK^T: D[m=kk 2x32][n=q 32]; A = K rows from LDS, B = Q regs
    f16v S[2] = {};
    __builtin_amdgcn_s_setprio(1);
#pragma unroll
    for (int ks = 0; ks < 8; ++ks) {
      int c16 = ks * 2 + half;
#pragma unroll
      for (int mt = 0; mt < 2; ++mt) {
        int r = mt * 32 + l31;
        bfrag kf = *(const bfrag*)&K_[r * 128 + ((c16 ^ (r & 15)) << 3)];
        S[mt] = __builtin_amdgcn_mfma_f32_32x32x16_bf16(kf, qf[ks], S[mt],
                                                        0, 0, 0);
      }
    }
    __builtin_amdgcn_s_setprio(0);
    // exp2 softmax: p = 2^S (log2e folded into Q scale -> exact e^s softmax)
    unsigned pd[16];  // bf16 pairs, pd[mt*8+i] = C regs (2i,2i+1) of tile mt
#pragma unroll
    for (int mt = 0; mt < 2; ++mt)
#pragma unroll
      for (int i = 0; i < 8; ++i) {
        float p0 = EXP2(S[mt][2 * i]);
        float p1 = EXP2(S[mt][2 * i + 1]);
        ls[i & 3] += p0 + p1;
        pd[mt * 8 + i] = cvt_pk_bf16(p0, p1);
      }
    // P C-layout -> B-layout: one v_permlane32_swap per reg pair.
#pragma unroll
    for (int mt = 0; mt < 2; ++mt)
#pragma unroll
      for (int s = 0; s < 2; ++s) {
        int base = mt * 8 + s * 4;
        unsigned a0 = pd[base + 0], a1 = pd[base + 1];
        unsigned c0 = pd[base + 2], c1 = pd[base + 3];
        asm("v_permlane32_swap_b32 %0, %1" : "+v"(a0), "+v"(c0));
        asm("v_permlane32_swap_b32 %0, %1" : "+v"(a1), "+v"(c1));
        union { unsigned u[4]; bfrag f; } pf;
        pf.u[0] = a0; pf.u[1] = a1; pf.u[2] = c0; pf.u[3] = c1;
        int c8 = (mt * 2 + s) * 2 + half;
        __builtin_amdgcn_s_setprio(1);
#pragma unroll
        for (int dt = 0; dt < 4; ++dt) {
          int r = dt * 32 + l31;
          bfrag vf = *(const bfrag*)&V_[r * 64 + ((c8 ^ (r & 7)) << 3)];
          o[dt] = __builtin_amdgcn_mfma_f32_32x32x16_bf16(vf, pf.f, o[dt],
                                                          0, 0, 0);
        }
        __builtin_amdgcn_s_setprio(0);
      }
  }
  // reduce l across the kk-halves (lane and lane^32 own complementary rows)
  float lrow = (ls[0] + ls[1]) + (ls[2] + ls[3]);
  lrow += __shfl_xor(lrow, 32);
  float inv = 1.f / lrow;
  unsigned short* Op = Ot + ((size_t)b * HW + q) * CCH + h * HD;
#pragma unroll
  for (int dt = 0; dt < 4; ++dt)
#pragma unroll
    for (int rg = 0; rg < 4; ++rg) {
      int d = dt * 32 + rg * 8 + half * 4;
      uint2 st;
      st.x = cvt_pk_bf16(o[dt][rg * 4 + 0] * inv, o[dt][rg * 4 + 1] * inv);
      st.y = cvt_pk_bf16(o[dt][rg * 4 + 2] * inv, o[dt][rg * 4 + 3] * inv);
      *(uint2*)&Op[d] = st;
    }
}

extern "C" void kernel_launch(void* const* d_in, const int* in_sizes, int n_in,
                              void* d_out, int out_size, void* d_ws,
                              size_t ws_size, hipStream_t stream) {
  const float* x = (const float*)d_in[0];
  const float* gamma = (const float*)d_in[1];
  const float* beta = (const float*)d_in[2];
  const float* wq = (const float*)d_in[3];
  const float* bq = (const float*)d_in[4];
  const float* wk = (const float*)d_in[5];
  const float* bk = (const float*)d_in[6];
  const float* wv = (const float*)d_in[7];
  const float* bv = (const float*)d_in[8];
  const float* wp = (const float*)d_in[9];
  const float* bp = (const float*)d_in[10];

  const size_t TS = (size_t)BATCH * HW * CCH;
  unsigned short* wB = (unsigned short*)d_ws;  // [4][512][512] bf16 (q,k,v,p)
  unsigned short* hn = wB + (size_t)4 * CCH * CCH;
  unsigned short* Qt = hn + TS;
  unsigned short* Kt = Qt + TS;
  unsigned short* Vc = Kt + TS;
  unsigned short* Ot = hn;  // reuse hn after QKV

  // 4 launches: gn+wcvt | QKV | attn | P
  gnw_kernel<<<dim3(1536), 256, 0, stream>>>(x, gamma, beta, hn,
                                             wq, wk, wv, wp, wB);
  qkv_kernel<<<dim3(8, 12, BATCH), 256, 0, stream>>>(hn, wB, bq, bk, bv,
                                                     Qt, Kt, Vc);
  attn_kernel<<<dim3(64, 8), 256, 0, stream>>>(Qt, Kt, Vc, Ot);
  mmp_kernel<<<dim3(8, 4, BATCH), 256, 0, stream>>>(
      Ot, wB + (size_t)3 * CCH * CCH, bp, x, (float*)d_out);
}

// Round 7
// 207.210 us; speedup vs baseline: 1.2816x; 1.2816x over previous
//
#include <hip/hip_runtime.h>
#include <math.h>

#define CCH 512
#define NH 4
#define HD 128
#define HW 1024
#define BATCH 16
#define EPS 1e-5f

typedef __attribute__((ext_vector_type(8))) short bfrag;    // 8 bf16 = 4 VGPRs
typedef __attribute__((ext_vector_type(4))) float f4;
typedef __attribute__((ext_vector_type(16))) float f16v;    // 32x32 accum

static __device__ __forceinline__ unsigned short f2bf(float f) {
  union { float f; unsigned u; } v;
  v.f = f;
  unsigned r = v.u + 0x7fff + ((v.u >> 16) & 1);  // RNE
  return (unsigned short)(r >> 16);
}
// packed f32x2 -> bf16x2 in one VALU op (gfx950). src0 -> low half.
static __device__ __forceinline__ unsigned cvt_pk_bf16(float a, float b) {
  unsigned r;
  asm("v_cvt_pk_bf16_f32 %0, %1, %2" : "=v"(r) : "v"(a), "v"(b));
  return r;
}
// exp2 via HW transcendental (no log2e multiply; folded into Q scale)
#if defined(__has_builtin) && __has_builtin(__builtin_amdgcn_exp2f)
#define EXP2(x) __builtin_amdgcn_exp2f(x)
#else
#define EXP2(x) __expf((x) * 0.6931471805599453f)  // e^(x ln2) == 2^x
#endif
// async global->LDS, 16B/lane. LDS dest = wave-uniform base + lane*16.
static __device__ __forceinline__ void ldg_lds16(const unsigned short* g,
                                                 unsigned short* l) {
  __builtin_amdgcn_global_load_lds(
      (const __attribute__((address_space(1))) unsigned int*)g,
      (__attribute__((address_space(3))) unsigned int*)l, 16, 0, 0);
}

// softmax scale folded into Q GEMM epilogue. Includes log2(e) so the
// attention softmax can use raw v_exp_f32 (2^x): 2^(s*log2e) == e^s exactly.
#define QSCALE (0.08838834764831845f * 1.4426950408889634f)

// main-loop LDS swizzle: rows r,r+4 no longer alias -> 2-way banks
#define SWZ(r) (((r) ^ ((r) >> 2)) & 3)

// ---------- fused: GroupNorm (blocks 0..511) + weight cvt (512..1535) -----
__global__ __launch_bounds__(256) void gnw_kernel(
    const float* __restrict__ x, const float* __restrict__ gamma,
    const float* __restrict__ beta, unsigned short* __restrict__ hn,
    const float* __restrict__ wq, const float* __restrict__ wk,
    const float* __restrict__ wv, const float* __restrict__ wp,
    unsigned short* __restrict__ wB) {
  int bx = blockIdx.x;
  int t = threadIdx.x;
  if (bx >= 512) {  // ---- weight fp32 -> bf16 ----
    int i0 = bx - 512;
    int mat = i0 >> 8;
    const float* srcs[4] = {wq, wk, wv, wp};
    const float* s = srcs[mat];
    unsigned short* dp = wB + (size_t)mat * CCH * CCH;
    int i = (i0 & 255) * 256 + t;
    f4 v = ((const f4*)s)[i];
    uint2 o;
    o.x = cvt_pk_bf16(v.x, v.y);
    o.y = cvt_pk_bf16(v.z, v.w);
    *(uint2*)&((ushort4*)dp)[i] = o;
    return;
  }
  // ---- GroupNorm -> position-major bf16 hn_t[b][hw][c] ----
  int b = bx >> 5, g = bx & 31;
  const float* xp = x + ((size_t)b * CCH + g * 16) * HW;
  float s = 0.f, ss = 0.f;
  const f4* xp4 = (const f4*)xp;
  f4 vv[16];
#pragma unroll
  for (int c = 0; c < 16; ++c) {
    f4 v = xp4[c * 256 + t];  // channel c, positions 4t..4t+3
    vv[c] = v;
    s += v.x + v.y + v.z + v.w;
    ss += v.x * v.x + v.y * v.y + v.z * v.z + v.w * v.w;
  }
#pragma unroll
  for (int off = 32; off > 0; off >>= 1) {
    s += __shfl_xor(s, off);
    ss += __shfl_xor(ss, off);
  }
  __shared__ float rs[4], rss[4];
  int w = t >> 6;
  if ((t & 63) == 0) { rs[w] = s; rss[w] = ss; }
  __syncthreads();
  s = rs[0] + rs[1] + rs[2] + rs[3];
  ss = rss[0] + rss[1] + rss[2] + rss[3];
  const float invn = 1.f / (16 * HW);
  float mean = s * invn;
  float var = ss * invn - mean * mean;
  float rstd = rsqrtf(var + EPS);
  float a_[16], b_[16];
#pragma unroll
  for (int c = 0; c < 16; ++c) {
    float gm = gamma[g * 16 + c] * rstd;
    a_[c] = gm;
    b_[c] = beta[g * 16 + c] - mean * gm;
  }
#pragma unroll
  for (int i = 0; i < 4; ++i) {
    int p = 4 * t + i;
    uint4 u0, u1;
    u0.x = cvt_pk_bf16(vv[0][i] * a_[0] + b_[0], vv[1][i] * a_[1] + b_[1]);
    u0.y = cvt_pk_bf16(vv[2][i] * a_[2] + b_[2], vv[3][i] * a_[3] + b_[3]);
    u0.z = cvt_pk_bf16(vv[4][i] * a_[4] + b_[4], vv[5][i] * a_[5] + b_[5]);
    u0.w = cvt_pk_bf16(vv[6][i] * a_[6] + b_[6], vv[7][i] * a_[7] + b_[7]);
    u1.x = cvt_pk_bf16(vv[8][i] * a_[8] + b_[8], vv[9][i] * a_[9] + b_[9]);
    u1.y = cvt_pk_bf16(vv[10][i] * a_[10] + b_[10], vv[11][i] * a_[11] + b_[11]);
    u1.z = cvt_pk_bf16(vv[12][i] * a_[12] + b_[12], vv[13][i] * a_[13] + b_[13]);
    u1.w = cvt_pk_bf16(vv[14][i] * a_[14] + b_[14], vv[15][i] * a_[15] + b_[15]);
    unsigned short* dst = hn + ((size_t)b * HW + p) * CCH + g * 16;
    *(uint4*)dst = u0;
    *(uint4*)(dst + 8) = u1;
  }
}

// ---------- MFMA GEMM, 3-buffer 2-deep pipeline (counted vmcnt) -----------
// D = Xt[b] @ W^T + bias over K=512, 128x128 block, 4 waves (64x64 each).
// COMPILE-TIME MODE (one epilogue + one MFMA orientation per instantiation;
// the r6 runtime-branch fusion spilled ~100MB of scratch -- never again):
// MODE 0: Q,K (mats 0/1 of Wb): SWAPPED operands -> D[m=ch][n=pos], then
//         LDS-transpose epilogue -> pos-major bf16 rows (full-line stores).
// MODE 1: V (Wb pre-offset): normal D[m=pos][n=ch] -> ch-major bf16.
// MODE 2: P (Wb pre-offset): normal -> fp32 ch-major + residual.
// Pipeline per iter: vmcnt(4) [tile k retired, k+1 in flight] -> raw
// s_barrier -> sched_barrier -> stage(k+2) -> ds_read+MFMA. Stage-to-use
// distance = 2 iters so L2/HBM latency hides; barrier never drains the
// in-flight prefetch. LDS 3 x 16KB = 48KB -> 3 blocks/CU.
template <int MODE>
__global__ __launch_bounds__(256, 3) void mm_kernel(
    const unsigned short* __restrict__ Xt, const unsigned short* __restrict__ Wb,
    const float* __restrict__ b0, const float* __restrict__ b1,
    const float* __restrict__ resid,
    unsigned short* __restrict__ O0, unsigned short* __restrict__ O1,
    float* __restrict__ Ofp) {
  int b = blockIdx.z;
  int p0 = blockIdx.x * 128;
  int c0g = blockIdx.y * 128;
  __shared__ __align__(16) unsigned short S_[24576];  // 48KB = 3 x (X8K|W8K)
  int t = threadIdx.x;
  int w = t >> 6, lane = t & 63, l15 = lane & 15, quad = lane >> 4;
  int wp = (w & 1) * 64, wc = (w >> 1) * 64;
  const unsigned short* Xb = Xt + (size_t)b * HW * CCH;
  const unsigned short* Wr = Wb + (size_t)c0g * CCH;
  f4 acc[4][4] = {};
  auto stage = [&](int k0, int bi) {
    unsigned short* Xd = S_ + bi * 8192;
    unsigned short* Wd = Xd + 4096;
#pragma unroll
    for (int j = 0; j < 2; ++j) {
      int chk = w * 2 + j;             // 1KB chunk = 16 rows x 64B
      int r = chk * 16 + (lane >> 2);
      int c = (lane & 3) ^ SWZ(r);     // XOR swizzle (bank-spread)
      ldg_lds16(&Xb[(size_t)(p0 + r) * CCH + k0 + c * 8], Xd + chk * 512);
      ldg_lds16(&Wr[(size_t)r * CCH + k0 + c * 8], Wd + chk * 512);
    }
  };
  stage(0, 0);
  stage(32, 1);
  int cur = 0;
  for (int k0 = 0; k0 < CCH; k0 += 32) {
    if (k0 < CCH - 32)
      asm volatile("s_waitcnt vmcnt(4)" ::: "memory");  // tile k done, k+1 fly
    else
      asm volatile("s_waitcnt vmcnt(0)" ::: "memory");
    __builtin_amdgcn_s_barrier();
    __builtin_amdgcn_sched_barrier(0);
    if (k0 + 64 < CCH) stage(k0 + 64, cur ? cur - 1 : 2);  // buf (cur+2)%3
    const unsigned short* Xc = S_ + cur * 8192;
    const unsigned short* Wc = Xc + 4096;
    bfrag af[4], bf[4];
#pragma unroll
    for (int pt = 0; pt < 4; ++pt) {
      int r = wp + pt * 16 + l15;
      af[pt] = *(const bfrag*)&Xc[r * 32 + ((quad ^ SWZ(r)) << 3)];
    }
#pragma unroll
    for (int ct = 0; ct < 4; ++ct) {
      int r = wc + ct * 16 + l15;
      bf[ct] = *(const bfrag*)&Wc[r * 32 + ((quad ^ SWZ(r)) << 3)];
    }
#pragma unroll
    for (int pt = 0; pt < 4; ++pt)
#pragma unroll
      for (int ct = 0; ct < 4; ++ct) {
        if (MODE == 0)  // swapped: D[m=ch][n=pos]
          acc[pt][ct] = __builtin_amdgcn_mfma_f32_16x16x32_bf16(
              bf[ct], af[pt], acc[pt][ct], 0, 0, 0);
        else
          acc[pt][ct] = __builtin_amdgcn_mfma_f32_16x16x32_bf16(
              af[pt], bf[ct], acc[pt][ct], 0, 0, 0);
      }
    cur = cur == 2 ? 0 : cur + 1;
  }
  if (MODE == 0) {
    // acc[pt][ct]: ch = wc+ct*16+quad*4+i, pos = wp+pt*16+l15
    int mat = c0g >> 9;
    int c0 = c0g & 511;
    const float* bias = mat ? b1 : b0;
    unsigned short* O = mat ? O1 : O0;
    const float sc = mat ? 1.0f : QSCALE;
    __syncthreads();  // all waves done reading k-loop LDS before reuse
    // LDS transpose buffer: [pos 128][ch 128] bf16 = 32KB (reuses S_).
    // 8B-granule XOR swizzle: granule g at row pos stored at g ^ ((pos&7)<<1)
#pragma unroll
    for (int ct = 0; ct < 4; ++ct) {
      f4 bi = *(const f4*)&bias[c0 + wc + ct * 16 + quad * 4];
      int g = (wc >> 2) + ct * 4 + quad;  // 8B granule index (0..31)
#pragma unroll
      for (int pt = 0; pt < 4; ++pt) {
        int pos = wp + pt * 16 + l15;
        f4 v = acc[pt][ct];
        uint2 d;
        d.x = cvt_pk_bf16((v.x + bi.x) * sc, (v.y + bi.y) * sc);
        d.y = cvt_pk_bf16((v.z + bi.z) * sc, (v.w + bi.w) * sc);
        int gs = g ^ ((pos & 7) << 1);
        *(uint2*)&S_[pos * 128 + gs * 4] = d;
      }
    }
    __syncthreads();
    unsigned short* Op = O + (size_t)b * HW * CCH;
#pragma unroll
    for (int it = 0; it < 8; ++it) {
      int row = w * 32 + it * 4 + (lane >> 4);   // wave w owns rows w*32..+31
      int g0 = (2 * l15) ^ ((row & 7) << 1);     // 16B granule (even ^ even)
      uint4 val = *(const uint4*)&S_[row * 128 + g0 * 4];
      *(uint4*)&Op[(size_t)(p0 + row) * CCH + c0 + l15 * 8] = val;
    }
  } else if (MODE == 1) {
    // normal: pos = p0+wp+pt*16+quad*4+i, ch = c0g+wc+ct*16+l15 (V ch-major)
#pragma unroll
    for (int ct = 0; ct < 4; ++ct) {
      int ch = c0g + wc + ct * 16 + l15;
      float bi = b0[ch];
      unsigned short* Op = O0 + (size_t)b * CCH * HW;
#pragma unroll
      for (int pt = 0; pt < 4; ++pt) {
        int pos = p0 + wp + pt * 16 + quad * 4;
        f4 v = acc[pt][ct];
        uint2 st;
        st.x = cvt_pk_bf16(v.x + bi, v.y + bi);
        st.y = cvt_pk_bf16(v.z + bi, v.w + bi);
        *(uint2*)&Op[(size_t)ch * HW + pos] = st;
      }
    }
  } else {
#pragma unroll
    for (int ct = 0; ct < 4; ++ct) {
      int ch = c0g + wc + ct * 16 + l15;
      float bi = b0[ch];
#pragma unroll
      for (int pt = 0; pt < 4; ++pt) {
        int pos = p0 + wp + pt * 16 + quad * 4;
        f4 v = acc[pt][ct];
        size_t off = (size_t)b * CCH * HW + (size_t)ch * HW + pos;
        float4 rv = *(const float4*)&resid[off];
        float4 st;
        st.x = v.x + bi + rv.x; st.y = v.y + bi + rv.y;
        st.z = v.z + bi + rv.z; st.w = v.w + bi + rv.w;
        *(float4*)&Ofp[off] = st;
      }
    }
  }
}

// ---------- Flash attention: frozen at round-5 banked best (~46.4us) ------
__global__ __launch_bounds__(256, 2) void attn_kernel(
    const unsigned short* __restrict__ Qt, const unsigned short* __restrict__ Kt,
    const unsigned short* __restrict__ Vc, unsigned short* __restrict__ Ot) {
  int bh = blockIdx.x;
  int b = bh >> 2, h = bh & 3;
  int q0 = blockIdx.y * 128;
  int t = threadIdx.x;
  int w = t >> 6, lane = t & 63;
  int l31 = lane & 31, half = lane >> 5;
  __shared__ __align__(16) unsigned short Ks[2][64 * 128];  // 2 x 16KB
  __shared__ __align__(16) unsigned short Vs[2][128 * 64];  // 2 x 16KB
  int q = q0 + w * 32 + l31;  // this lane's query
  const unsigned short* Kbase = Kt + (size_t)b * HW * CCH + h * HD;
  const unsigned short* Vbase = Vc + ((size_t)b * CCH + h * HD) * HW;
  // Q B-frags: B[k=ks*16+half*8+j][n=q], loop-invariant
  bfrag qf[8];
#pragma unroll
  for (int ks = 0; ks < 8; ++ks)
    qf[ks] = *(const bfrag*)&Qt[((size_t)b * HW + q) * CCH + h * HD +
                                ks * 16 + half * 8];
  f16v o[4] = {};   // PV accum: D[m=d (4x32)][n=q]
  float ls[4] = {}; // rotating partial row-sums (short dep chains)
  // staging: wave w owns chunks 4w..4w+3 of Ks and of Vs (1KB each)
  auto stage = [&](int kt, int bi) {
    int kk0 = kt * 64;
#pragma unroll
    for (int j = 0; j < 4; ++j) {
      int chk = w * 4 + j;
      {  // Ks chunk: 4 rows x 256B
        int r = chk * 4 + (lane >> 4);
        int c = (lane & 15) ^ (r & 15);
        ldg_lds16(&Kbase[(size_t)(kk0 + r) * CCH + c * 8], &Ks[bi][chk * 512]);
      }
      {  // Vs chunk: 8 rows x 128B
        int r = chk * 8 + (lane >> 3);
        int c = (lane & 7) ^ (r & 7);
        ldg_lds16(&Vbase[(size_t)r * HW + kk0 + c * 8], &Vs[bi][chk * 512]);
      }
    }
  };
  stage(0, 0);
  for (int kt = 0; kt < 16; ++kt) {
    __syncthreads();  // stage(kt) complete everywhere; prev-iter reads done
    if (kt < 15) stage(kt + 1, (kt + 1) & 1);  // overlaps compute below
    const unsigned short* K_ = Ks[kt & 1];
    const unsigned short* V_ = Vs[kt & 1];
    // QK^T: D[m=kk 2x32][n=q 32]; A = K rows from LDS, B = Q regs
    f16v S[2] = {};
    __builtin_amdgcn_s_setprio(1);
#pragma unroll
    for (int ks = 0; ks < 8; ++ks) {
      int c16 = ks * 2 + half;
#pragma unroll
      for (int mt = 0; mt < 2; ++mt) {
        int r = mt * 32 + l31;
        bfrag kf = *(const bfrag*)&K_[r * 128 + ((c16 ^ (r & 15)) << 3)];
        S[mt] = __builtin_amdgcn_mfma_f32_32x32x16_bf16(kf, qf[ks], S[mt],
                                                        0, 0, 0);
      }
    }
    __builtin_amdgcn_s_setprio(0);
    // exp2 softmax: p = 2^S (log2e folded into Q scale -> exact e^s softmax)
    unsigned pd[16];  // bf16 pairs, pd[mt*8+i] = C regs (2i,2i+1) of tile mt
#pragma unroll
    for (int mt = 0; mt < 2; ++mt)
#pragma unroll
      for (int i = 0; i < 8; ++i) {
        float p0 = EXP2(S[mt][2 * i]);
        float p1 = EXP2(S[mt][2 * i + 1]);
        ls[i & 3] += p0 + p1;
        pd[mt * 8 + i] = cvt_pk_bf16(p0, p1);
      }
    // P C-layout -> B-layout: one v_permlane32_swap per reg pair.
#pragma unroll
    for (int mt = 0; mt < 2; ++mt)
#pragma unroll
      for (int s = 0; s < 2; ++s) {
        int base = mt * 8 + s * 4;
        unsigned a0 = pd[base + 0], a1 = pd[base + 1];
        unsigned c0 = pd[base + 2], c1 = pd[base + 3];
        asm("v_permlane32_swap_b32 %0, %1" : "+v"(a0), "+v"(c0));
        asm("v_permlane32_swap_b32 %0, %1" : "+v"(a1), "+v"(c1));
        union { unsigned u[4]; bfrag f; } pf;
        pf.u[0] = a0; pf.u[1] = a1; pf.u[2] = c0; pf.u[3] = c1;
        int c8 = (mt * 2 + s) * 2 + half;
        __builtin_amdgcn_s_setprio(1);
#pragma unroll
        for (int dt = 0; dt < 4; ++dt) {
          int r = dt * 32 + l31;
          bfrag vf = *(const bfrag*)&V_[r * 64 + ((c8 ^ (r & 7)) << 3)];
          o[dt] = __builtin_amdgcn_mfma_f32_32x32x16_bf16(vf, pf.f, o[dt],
                                                          0, 0, 0);
        }
        __builtin_amdgcn_s_setprio(0);
      }
  }
  // reduce l across the kk-halves (lane and lane^32 own complementary rows)
  float lrow = (ls[0] + ls[1]) + (ls[2] + ls[3]);
  lrow += __shfl_xor(lrow, 32);
  float inv = 1.f / lrow;
  unsigned short* Op = Ot + ((size_t)b * HW + q) * CCH + h * HD;
#pragma unroll
  for (int dt = 0; dt < 4; ++dt)
#pragma unroll
    for (int rg = 0; rg < 4; ++rg) {
      int d = dt * 32 + rg * 8 + half * 4;
      uint2 st;
      st.x = cvt_pk_bf16(o[dt][rg * 4 + 0] * inv, o[dt][rg * 4 + 1] * inv);
      st.y = cvt_pk_bf16(o[dt][rg * 4 + 2] * inv, o[dt][rg * 4 + 3] * inv);
      *(uint2*)&Op[d] = st;
    }
}

extern "C" void kernel_launch(void* const* d_in, const int* in_sizes, int n_in,
                              void* d_out, int out_size, void* d_ws,
                              size_t ws_size, hipStream_t stream) {
  const float* x = (const float*)d_in[0];
  const float* gamma = (const float*)d_in[1];
  const float* beta = (const float*)d_in[2];
  const float* wq = (const float*)d_in[3];
  const float* bq = (const float*)d_in[4];
  const float* wk = (const float*)d_in[5];
  const float* bk = (const float*)d_in[6];
  const float* wv = (const float*)d_in[7];
  const float* bv = (const float*)d_in[8];
  const float* wp = (const float*)d_in[9];
  const float* bp = (const float*)d_in[10];

  const size_t TS = (size_t)BATCH * HW * CCH;
  unsigned short* wB = (unsigned short*)d_ws;  // [4][512][512] bf16 (q,k,v,p)
  unsigned short* hn = wB + (size_t)4 * CCH * CCH;
  unsigned short* Qt = hn + TS;
  unsigned short* Kt = Qt + TS;
  unsigned short* Vc = Kt + TS;
  unsigned short* Ot = hn;  // reuse hn after QKV

  // 5 launches: gn+wcvt | QK | V | attn | P
  gnw_kernel<<<dim3(1536), 256, 0, stream>>>(x, gamma, beta, hn,
                                             wq, wk, wv, wp, wB);
  mm_kernel<0><<<dim3(8, 8, BATCH), 256, 0, stream>>>(
      hn, wB, bq, bk, nullptr, Qt, Kt, nullptr);
  mm_kernel<1><<<dim3(8, 4, BATCH), 256, 0, stream>>>(
      hn, wB + (size_t)2 * CCH * CCH, bv, nullptr, nullptr, Vc, nullptr,
      nullptr);
  attn_kernel<<<dim3(64, 8), 256, 0, stream>>>(Qt, Kt, Vc, Ot);
  mm_kernel<2><<<dim3(8, 4, BATCH), 256, 0, stream>>>(
      Ot, wB + (size_t)3 * CCH * CCH, bp, nullptr, x, nullptr, nullptr,
      (float*)d_out);
}

// Round 8
// 205.803 us; speedup vs baseline: 1.2903x; 1.0068x over previous
//
#include <hip/hip_runtime.h>
#include <math.h>

#define CCH 512
#define NH 4
#define HD 128
#define HW 1024
#define BATCH 16
#define EPS 1e-5f

typedef __attribute__((ext_vector_type(8))) short bfrag;    // 8 bf16 = 4 VGPRs
typedef __attribute__((ext_vector_type(4))) float f4;
typedef __attribute__((ext_vector_type(16))) float f16v;    // 32x32 accum

static __device__ __forceinline__ unsigned short f2bf(float f) {
  union { float f; unsigned u; } v;
  v.f = f;
  unsigned r = v.u + 0x7fff + ((v.u >> 16) & 1);  // RNE
  return (unsigned short)(r >> 16);
}
// packed f32x2 -> bf16x2 in one VALU op (gfx950). src0 -> low half.
static __device__ __forceinline__ unsigned cvt_pk_bf16(float a, float b) {
  unsigned r;
  asm("v_cvt_pk_bf16_f32 %0, %1, %2" : "=v"(r) : "v"(a), "v"(b));
  return r;
}
// exp2 via HW transcendental (no log2e multiply; folded into Q scale)
#if defined(__has_builtin) && __has_builtin(__builtin_amdgcn_exp2f)
#define EXP2(x) __builtin_amdgcn_exp2f(x)
#else
#define EXP2(x) __expf((x) * 0.6931471805599453f)  // e^(x ln2) == 2^x
#endif
// async global->LDS, 16B/lane. LDS dest = wave-uniform base + lane*16.
static __device__ __forceinline__ void ldg_lds16(const unsigned short* g,
                                                 unsigned short* l) {
  __builtin_amdgcn_global_load_lds(
      (const __attribute__((address_space(1))) unsigned int*)g,
      (__attribute__((address_space(3))) unsigned int*)l, 16, 0, 0);
}

// softmax scale folded into Q GEMM epilogue. Includes log2(e) so the
// attention softmax can use raw v_exp_f32 (2^x): 2^(s*log2e) == e^s exactly.
#define QSCALE (0.08838834764831845f * 1.4426950408889634f)

// 128-tile main-loop LDS swizzle (mm_kernel): rows r,r+4 no longer alias
#define SWZ(r) (((r) ^ ((r) >> 2)) & 3)

// ---------- fused: GroupNorm (blocks 0..511) + weight cvt (512..1535) -----
__global__ __launch_bounds__(256) void gnw_kernel(
    const float* __restrict__ x, const float* __restrict__ gamma,
    const float* __restrict__ beta, unsigned short* __restrict__ hn,
    const float* __restrict__ wq, const float* __restrict__ wk,
    const float* __restrict__ wv, const float* __restrict__ wp,
    unsigned short* __restrict__ wB) {
  int bx = blockIdx.x;
  int t = threadIdx.x;
  if (bx >= 512) {  // ---- weight fp32 -> bf16 ----
    int i0 = bx - 512;
    int mat = i0 >> 8;
    const float* srcs[4] = {wq, wk, wv, wp};
    const float* s = srcs[mat];
    unsigned short* dp = wB + (size_t)mat * CCH * CCH;
    int i = (i0 & 255) * 256 + t;
    f4 v = ((const f4*)s)[i];
    uint2 o;
    o.x = cvt_pk_bf16(v.x, v.y);
    o.y = cvt_pk_bf16(v.z, v.w);
    *(uint2*)&((ushort4*)dp)[i] = o;
    return;
  }
  // ---- GroupNorm -> position-major bf16 hn_t[b][hw][c] ----
  int b = bx >> 5, g = bx & 31;
  const float* xp = x + ((size_t)b * CCH + g * 16) * HW;
  float s = 0.f, ss = 0.f;
  const f4* xp4 = (const f4*)xp;
  f4 vv[16];
#pragma unroll
  for (int c = 0; c < 16; ++c) {
    f4 v = xp4[c * 256 + t];  // channel c, positions 4t..4t+3
    vv[c] = v;
    s += v.x + v.y + v.z + v.w;
    ss += v.x * v.x + v.y * v.y + v.z * v.z + v.w * v.w;
  }
#pragma unroll
  for (int off = 32; off > 0; off >>= 1) {
    s += __shfl_xor(s, off);
    ss += __shfl_xor(ss, off);
  }
  __shared__ float rs[4], rss[4];
  int w = t >> 6;
  if ((t & 63) == 0) { rs[w] = s; rss[w] = ss; }
  __syncthreads();
  s = rs[0] + rs[1] + rs[2] + rs[3];
  ss = rss[0] + rss[1] + rss[2] + rss[3];
  const float invn = 1.f / (16 * HW);
  float mean = s * invn;
  float var = ss * invn - mean * mean;
  float rstd = rsqrtf(var + EPS);
  float a_[16], b_[16];
#pragma unroll
  for (int c = 0; c < 16; ++c) {
    float gm = gamma[g * 16 + c] * rstd;
    a_[c] = gm;
    b_[c] = beta[g * 16 + c] - mean * gm;
  }
#pragma unroll
  for (int i = 0; i < 4; ++i) {
    int p = 4 * t + i;
    uint4 u0, u1;
    u0.x = cvt_pk_bf16(vv[0][i] * a_[0] + b_[0], vv[1][i] * a_[1] + b_[1]);
    u0.y = cvt_pk_bf16(vv[2][i] * a_[2] + b_[2], vv[3][i] * a_[3] + b_[3]);
    u0.z = cvt_pk_bf16(vv[4][i] * a_[4] + b_[4], vv[5][i] * a_[5] + b_[5]);
    u0.w = cvt_pk_bf16(vv[6][i] * a_[6] + b_[6], vv[7][i] * a_[7] + b_[7]);
    u1.x = cvt_pk_bf16(vv[8][i] * a_[8] + b_[8], vv[9][i] * a_[9] + b_[9]);
    u1.y = cvt_pk_bf16(vv[10][i] * a_[10] + b_[10], vv[11][i] * a_[11] + b_[11]);
    u1.z = cvt_pk_bf16(vv[12][i] * a_[12] + b_[12], vv[13][i] * a_[13] + b_[13]);
    u1.w = cvt_pk_bf16(vv[14][i] * a_[14] + b_[14], vv[15][i] * a_[15] + b_[15]);
    unsigned short* dst = hn + ((size_t)b * HW + p) * CCH + g * 16;
    *(uint4*)dst = u0;
    *(uint4*)(dst + 8) = u1;
  }
}

// ---------- QK GEMM: 256x256 tile, BK=64, 4-phase zigzag schedule ---------
// 512 thr = 8 waves (2 pos-groups x 4 ch-groups), per-wave 128pos x 64ch,
// acc 8x4 f4 = 128 VGPR (cap 256 via launch_bounds -> no spill).
// SWAPPED MFMA -> D[m=ch][n=pos]; two-pass LDS-transpose epilogue gives
// pos-major full-line stores. LDS 128KB = 2 dbuf x (A 32KB + B 32KB).
// Per K-tile (BK=64): 4 phases in zigzag quadrant order so frag reads stay
// minimal (24 b128/K-tile) and each phase interleaves
// {2 global_load_lds of next tile || ds_reads || barrier || setprio+16 MFMA}.
// Iter-end vmcnt(0) waits only loads issued >=2 phases earlier.
// grid (4 pos, 4 ch(2 mats x 2), 16 batch) = 256 blocks = 1/CU.
__global__ __launch_bounds__(512, 2) void qk_kernel(
    const unsigned short* __restrict__ Xt, const unsigned short* __restrict__ Wb,
    const float* __restrict__ bq, const float* __restrict__ bk,
    unsigned short* __restrict__ Qt, unsigned short* __restrict__ Kt) {
  int b = blockIdx.z;
  int p0 = blockIdx.x * 256;
  int c0g = blockIdx.y * 256;  // 0..768 over stacked Q(512)+K(512) rows
  __shared__ __align__(16) unsigned short S_[65536];  // 128KB, 2x(A16K|B16K)
  int t = threadIdx.x;
  int w = t >> 6, lane = t & 63, l15 = lane & 15, quad = lane >> 4;
  int wp = (w & 1) * 128;   // pos-group
  int wc = (w >> 1) * 64;   // ch-group
  const unsigned short* Xb = Xt + (size_t)b * HW * CCH;
  const unsigned short* Wr = Wb + (size_t)c0g * CCH;  // mats 0/1 contiguous
  f4 acc[8][4] = {};  // [pos-tile 8][ch-tile 4]
  // staging: per K-tile, A = 32 chunks (8 rows x 128B), B = 32 chunks;
  // wave w stages A-chunks 4w..4w+3 and B-chunks 4w..4w+3 (1 A + 1 B per
  // phase). LDS dest linear; source col pre-XOR'd (involution, read side
  // applies the same XOR).
  auto stageA = [&](int k0, int bi, int j) {
    int chk = w * 4 + j;
    int r = chk * 8 + (lane >> 3);
    int c = (lane & 7) ^ (r & 7);
    ldg_lds16(&Xb[(size_t)(p0 + r) * CCH + k0 + c * 8],
              S_ + bi * 32768 + chk * 512);
  };
  auto stageB = [&](int k0, int bi, int j) {
    int chk = w * 4 + j;
    int r = chk * 8 + (lane >> 3);
    int c = (lane & 7) ^ (r & 7);
    ldg_lds16(&Wr[(size_t)r * CCH + k0 + c * 8],
              S_ + bi * 32768 + 16384 + chk * 512);
  };
#pragma unroll
  for (int j = 0; j < 4; ++j) { stageA(0, 0, j); stageB(0, 0, j); }
  __syncthreads();  // tile 0 staged everywhere
  for (int kt = 0; kt < 8; ++kt) {
    int cur = kt & 1;
    const unsigned short* A_ = S_ + cur * 32768;
    const unsigned short* B_ = A_ + 16384;
    int k0n = kt * 64 + 64;
    bool pre = kt < 7;
    bfrag af0[8], af1[8], bf[4];
    // -- phase 0: af half0 (pos 0-63) + bf pair0 (ch 0-31); quad (pt0-3,ct0-1)
    if (pre) { stageA(k0n, cur ^ 1, 0); stageB(k0n, cur ^ 1, 0); }
#pragma unroll
    for (int pt = 0; pt < 4; ++pt)
#pragma unroll
      for (int ks = 0; ks < 2; ++ks) {
        int r = wp + pt * 16 + l15;
        af0[pt * 2 + ks] =
            *(const bfrag*)&A_[r * 64 + (((ks * 4 + quad) ^ (r & 7)) << 3)];
      }
#pragma unroll
    for (int ct = 0; ct < 2; ++ct)
#pragma unroll
      for (int ks = 0; ks < 2; ++ks) {
        int r = wc + ct * 16 + l15;
        bf[ct * 2 + ks] =
            *(const bfrag*)&B_[r * 64 + (((ks * 4 + quad) ^ (r & 7)) << 3)];
      }
    __builtin_amdgcn_s_barrier();
    __builtin_amdgcn_s_setprio(1);
#pragma unroll
    for (int pt = 0; pt < 4; ++pt)
#pragma unroll
      for (int ct = 0; ct < 2; ++ct)
#pragma unroll
        for (int ks = 0; ks < 2; ++ks)
          acc[pt][ct] = __builtin_amdgcn_mfma_f32_16x16x32_bf16(
              bf[ct * 2 + ks], af0[pt * 2 + ks], acc[pt][ct], 0, 0, 0);
    __builtin_amdgcn_s_setprio(0);
    // -- phase 1: af half1 (pos 64-127); reuse bf pair0; quad (pt4-7,ct0-1)
    if (pre) { stageA(k0n, cur ^ 1, 1); stageB(k0n, cur ^ 1, 1); }
#pragma unroll
    for (int pt = 0; pt < 4; ++pt)
#pragma unroll
      for (int ks = 0; ks < 2; ++ks) {
        int r = wp + 64 + pt * 16 + l15;
        af1[pt * 2 + ks] =
            *(const bfrag*)&A_[r * 64 + (((ks * 4 + quad) ^ (r & 7)) << 3)];
      }
    __builtin_amdgcn_s_barrier();
    __builtin_amdgcn_s_setprio(1);
#pragma unroll
    for (int pt = 0; pt < 4; ++pt)
#pragma unroll
      for (int ct = 0; ct < 2; ++ct)
#pragma unroll
        for (int ks = 0; ks < 2; ++ks)
          acc[pt + 4][ct] = __builtin_amdgcn_mfma_f32_16x16x32_bf16(
              bf[ct * 2 + ks], af1[pt * 2 + ks], acc[pt + 4][ct], 0, 0, 0);
    __builtin_amdgcn_s_setprio(0);
    // -- phase 2: bf pair1 (ch 32-63, overwrites bf); reuse af1
    if (pre) { stageA(k0n, cur ^ 1, 2); stageB(k0n, cur ^ 1, 2); }
#pragma unroll
    for (int ct = 0; ct < 2; ++ct)
#pragma unroll
      for (int ks = 0; ks < 2; ++ks) {
        int r = wc + (ct + 2) * 16 + l15;
        bf[ct * 2 + ks] =
            *(const bfrag*)&B_[r * 64 + (((ks * 4 + quad) ^ (r & 7)) << 3)];
      }
    __builtin_amdgcn_s_barrier();
    __builtin_amdgcn_s_setprio(1);
#pragma unroll
    for (int pt = 0; pt < 4; ++pt)
#pragma unroll
      for (int ct = 0; ct < 2; ++ct)
#pragma unroll
        for (int ks = 0; ks < 2; ++ks)
          acc[pt + 4][ct + 2] = __builtin_amdgcn_mfma_f32_16x16x32_bf16(
              bf[ct * 2 + ks], af1[pt * 2 + ks], acc[pt + 4][ct + 2], 0, 0, 0);
    __builtin_amdgcn_s_setprio(0);
    // -- phase 3: reuse af0 + bf pair1 (no ds_reads)
    if (pre) { stageA(k0n, cur ^ 1, 3); stageB(k0n, cur ^ 1, 3); }
    __builtin_amdgcn_s_barrier();
    __builtin_amdgcn_s_setprio(1);
#pragma unroll
    for (int pt = 0; pt < 4; ++pt)
#pragma unroll
      for (int ct = 0; ct < 2; ++ct)
#pragma unroll
        for (int ks = 0; ks < 2; ++ks)
          acc[pt][ct + 2] = __builtin_amdgcn_mfma_f32_16x16x32_bf16(
              bf[ct * 2 + ks], af0[pt * 2 + ks], acc[pt][ct + 2], 0, 0, 0);
    __builtin_amdgcn_s_setprio(0);
    // iter boundary: this iter's 8 stage-loads retired (oldest issued 4
    // phases ago), then barrier -> buf cur^1 fully visible for next iter.
    if (pre) {
      asm volatile("s_waitcnt vmcnt(0)" ::: "memory");
      __builtin_amdgcn_s_barrier();
    }
  }
  // ---- two-pass LDS-transpose epilogue (per 128-ch half) ----
  __syncthreads();  // all k-loop LDS reads done before reuse
  int mat = c0g >> 9;
  int c0 = c0g & 511;
  const float* bias = mat ? bk : bq;
  unsigned short* O = mat ? Kt : Qt;
  const float sc = mat ? 1.0f : QSCALE;
  unsigned short* Op = O + (size_t)b * HW * CCH;
  int wcl = wc & 127;
  int myhalf = wc >> 7;
#pragma unroll
  for (int h = 0; h < 2; ++h) {
    if (myhalf == h) {
      // acc -> LDS [pos 256][ch 128] bf16 (64KB), 8B-granule XOR swizzle
#pragma unroll
      for (int ct = 0; ct < 4; ++ct) {
        f4 bi = *(const f4*)&bias[c0 + h * 128 + wcl + ct * 16 + quad * 4];
        int g = (wcl >> 2) + ct * 4 + quad;  // 8B granule (0..31)
#pragma unroll
        for (int pt = 0; pt < 8; ++pt) {
          int pos = wp + pt * 16 + l15;
          f4 v = acc[pt][ct];
          uint2 d;
          d.x = cvt_pk_bf16((v.x + bi.x) * sc, (v.y + bi.y) * sc);
          d.y = cvt_pk_bf16((v.z + bi.z) * sc, (v.w + bi.w) * sc);
          int gs = g ^ ((pos & 7) << 1);
          *(uint2*)&S_[pos * 128 + gs * 4] = d;
        }
      }
    }
    __syncthreads();
#pragma unroll
    for (int it = 0; it < 8; ++it) {
      int row = w * 32 + it * 4 + (lane >> 4);   // 8 waves x 32 rows = 256
      int g0 = (2 * l15) ^ ((row & 7) << 1);     // 16B granule (even ^ even)
      uint4 val = *(const uint4*)&S_[row * 128 + g0 * 4];
      *(uint4*)&Op[(size_t)(p0 + row) * CCH + c0 + h * 128 + l15 * 8] = val;
    }
    if (h == 0) __syncthreads();  // pass-0 reads done before pass-1 writes
  }
}

// ---------- MFMA GEMM, 3-buffer 2-deep pipeline (counted vmcnt) -----------
// MODE 1: V (Wb pre-offset): normal D[m=pos][n=ch] -> ch-major bf16.
// MODE 2: P (Wb pre-offset): normal -> fp32 ch-major + residual.
template <int MODE>
__global__ __launch_bounds__(256, 3) void mm_kernel(
    const unsigned short* __restrict__ Xt, const unsigned short* __restrict__ Wb,
    const float* __restrict__ b0, const float* __restrict__ resid,
    unsigned short* __restrict__ O0, float* __restrict__ Ofp) {
  int b = blockIdx.z;
  int p0 = blockIdx.x * 128;
  int c0g = blockIdx.y * 128;
  __shared__ __align__(16) unsigned short S_[24576];  // 48KB = 3 x (X8K|W8K)
  int t = threadIdx.x;
  int w = t >> 6, lane = t & 63, l15 = lane & 15, quad = lane >> 4;
  int wp = (w & 1) * 64, wc = (w >> 1) * 64;
  const unsigned short* Xb = Xt + (size_t)b * HW * CCH;
  const unsigned short* Wr = Wb + (size_t)c0g * CCH;
  f4 acc[4][4] = {};
  auto stage = [&](int k0, int bi) {
    unsigned short* Xd = S_ + bi * 8192;
    unsigned short* Wd = Xd + 4096;
#pragma unroll
    for (int j = 0; j < 2; ++j) {
      int chk = w * 2 + j;             // 1KB chunk = 16 rows x 64B
      int r = chk * 16 + (lane >> 2);
      int c = (lane & 3) ^ SWZ(r);     // XOR swizzle (bank-spread)
      ldg_lds16(&Xb[(size_t)(p0 + r) * CCH + k0 + c * 8], Xd + chk * 512);
      ldg_lds16(&Wr[(size_t)r * CCH + k0 + c * 8], Wd + chk * 512);
    }
  };
  stage(0, 0);
  stage(32, 1);
  int cur = 0;
  for (int k0 = 0; k0 < CCH; k0 += 32) {
    if (k0 < CCH - 32)
      asm volatile("s_waitcnt vmcnt(4)" ::: "memory");  // tile k done, k+1 fly
    else
      asm volatile("s_waitcnt vmcnt(0)" ::: "memory");
    __builtin_amdgcn_s_barrier();
    __builtin_amdgcn_sched_barrier(0);
    if (k0 + 64 < CCH) stage(k0 + 64, cur ? cur - 1 : 2);  // buf (cur+2)%3
    const unsigned short* Xc = S_ + cur * 8192;
    const unsigned short* Wc = Xc + 4096;
    bfrag af[4], bf[4];
#pragma unroll
    for (int pt = 0; pt < 4; ++pt) {
      int r = wp + pt * 16 + l15;
      af[pt] = *(const bfrag*)&Xc[r * 32 + ((quad ^ SWZ(r)) << 3)];
    }
#pragma unroll
    for (int ct = 0; ct < 4; ++ct) {
      int r = wc + ct * 16 + l15;
      bf[ct] = *(const bfrag*)&Wc[r * 32 + ((quad ^ SWZ(r)) << 3)];
    }
#pragma unroll
    for (int pt = 0; pt < 4; ++pt)
#pragma unroll
      for (int ct = 0; ct < 4; ++ct)
        acc[pt][ct] = __builtin_amdgcn_mfma_f32_16x16x32_bf16(
            af[pt], bf[ct], acc[pt][ct], 0, 0, 0);
    cur = cur == 2 ? 0 : cur + 1;
  }
  if (MODE == 1) {
    // pos = p0+wp+pt*16+quad*4+i, ch = c0g+wc+ct*16+l15 (V ch-major)
#pragma unroll
    for (int ct = 0; ct < 4; ++ct) {
      int ch = c0g + wc + ct * 16 + l15;
      float bi = b0[ch];
      unsigned short* Op = O0 + (size_t)b * CCH * HW;
#pragma unroll
      for (int pt = 0; pt < 4; ++pt) {
        int pos = p0 + wp + pt * 16 + quad * 4;
        f4 v = acc[pt][ct];
        uint2 st;
        st.x = cvt_pk_bf16(v.x + bi, v.y + bi);
        st.y = cvt_pk_bf16(v.z + bi, v.w + bi);
        *(uint2*)&Op[(size_t)ch * HW + pos] = st;
      }
    }
  } else {
#pragma unroll
    for (int ct = 0; ct < 4; ++ct) {
      int ch = c0g + wc + ct * 16 + l15;
      float bi = b0[ch];
#pragma unroll
      for (int pt = 0; pt < 4; ++pt) {
        int pos = p0 + wp + pt * 16 + quad * 4;
        f4 v = acc[pt][ct];
        size_t off = (size_t)b * CCH * HW + (size_t)ch * HW + pos;
        float4 rv = *(const float4*)&resid[off];
        float4 st;
        st.x = v.x + bi + rv.x; st.y = v.y + bi + rv.y;
        st.z = v.z + bi + rv.z; st.w = v.w + bi + rv.w;
        *(float4*)&Ofp[off] = st;
      }
    }
  }
}

// ---------- Flash attention: frozen (best ~46-48us) ------------------------
__global__ __launch_bounds__(256, 2) void attn_kernel(
    const unsigned short* __restrict__ Qt, const unsigned short* __restrict__ Kt,
    const unsigned short* __restrict__ Vc, unsigned short* __restrict__ Ot) {
  int bh = blockIdx.x;
  int b = bh >> 2, h = bh & 3;
  int q0 = blockIdx.y * 128;
  int t = threadIdx.x;
  int w = t >> 6, lane = t & 63;
  int l31 = lane & 31, half = lane >> 5;
  __shared__ __align__(16) unsigned short Ks[2][64 * 128];  // 2 x 16KB
  __shared__ __align__(16) unsigned short Vs[2][128 * 64];  // 2 x 16KB
  int q = q0 + w * 32 + l31;  // this lane's query
  const unsigned short* Kbase = Kt + (size_t)b * HW * CCH + h * HD;
  const unsigned short* Vbase = Vc + ((size_t)b * CCH + h * HD) * HW;
  // Q B-frags: B[k=ks*16+half*8+j][n=q], loop-invariant
  bfrag qf[8];
#pragma unroll
  for (int ks = 0; ks < 8; ++ks)
    qf[ks] = *(const bfrag*)&Qt[((size_t)b * HW + q) * CCH + h * HD +
                                ks * 16 + half * 8];
  f16v o[4] = {};   // PV accum: D[m=d (4x32)][n=q]
  float ls[4] = {}; // rotating partial row-sums (short dep chains)
  // staging: wave w owns chunks 4w..4w+3 of Ks and of Vs (1KB each)
  auto stage = [&](int kt, int bi) {
    int kk0 = kt * 64;
#pragma unroll
    for (int j = 0; j < 4; ++j) {
      int chk = w * 4 + j;
      {  // Ks chunk: 4 rows x 256B
        int r = chk * 4 + (lane >> 4);
        int c = (lane & 15) ^ (r & 15);
        ldg_lds16(&Kbase[(size_t)(kk0 + r) * CCH + c * 8], &Ks[bi][chk * 512]);
      }
      {  // Vs chunk: 8 rows x 128B
        int r = chk * 8 + (lane >> 3);
        int c = (lane & 7) ^ (r & 7);
        ldg_lds16(&Vbase[(size_t)r * HW + kk0 + c * 8], &Vs[bi][chk * 512]);
      }
    }
  };
  stage(0, 0);
  for (int kt = 0; kt < 16; ++kt) {
    __syncthreads();  // stage(kt) complete everywhere; prev-iter reads done
    if (kt < 15) stage(kt + 1, (kt + 1) & 1);  // overlaps compute below
    const unsigned short* K_ = Ks[kt & 1];
    const unsigned short* V_ = Vs[kt & 1];
    // QK^T: D[m=kk 2x32][n=q 32]; A = K rows from LDS, B = Q regs
    f16v S[2] = {};
    __builtin_amdgcn_s_setprio(1);
#pragma unroll
    for (int ks = 0; ks < 8; ++ks) {
      int c16 = ks * 2 + half;
#pragma unroll
      for (int mt = 0; mt < 2; ++mt) {
        int r = mt * 32 + l31;
        bfrag kf = *(const bfrag*)&K_[r * 128 + ((c16 ^ (r & 15)) << 3)];
        S[mt] = __builtin_amdgcn_mfma_f32_32x32x16_bf16(kf, qf[ks], S[mt],
                                                        0, 0, 0);
      }
    }
    __builtin_amdgcn_s_setprio(0);
    // exp2 softmax: p = 2^S (log2e folded into Q scale -> exact e^s softmax)
    unsigned pd[16];  // bf16 pairs, pd[mt*8+i] = C regs (2i,2i+1) of tile mt
#pragma unroll
    for (int mt = 0; mt < 2; ++mt)
#pragma unroll
      for (int i = 0; i < 8; ++i) {
        float p0 = EXP2(S[mt][2 * i]);
        float p1 = EXP2(S[mt][2 * i + 1]);
        ls[i & 3] += p0 + p1;
        pd[mt * 8 + i] = cvt_pk_bf16(p0, p1);
      }
    // P C-layout -> B-layout: one v_permlane32_swap per reg pair.
#pragma unroll
    for (int mt = 0; mt < 2; ++mt)
#pragma unroll
      for (int s = 0; s < 2; ++s) {
        int base = mt * 8 + s * 4;
        unsigned a0 = pd[base + 0], a1 = pd[base + 1];
        unsigned c0 = pd[base + 2], c1 = pd[base + 3];
        asm("v_permlane32_swap_b32 %0, %1" : "+v"(a0), "+v"(c0));
        asm("v_permlane32_swap_b32 %0, %1" : "+v"(a1), "+v"(c1));
        union { unsigned u[4]; bfrag f; } pf;
        pf.u[0] = a0; pf.u[1] = a1; pf.u[2] = c0; pf.u[3] = c1;
        int c8 = (mt * 2 + s) * 2 + half;
        __builtin_amdgcn_s_setprio(1);
#pragma unroll
        for (int dt = 0; dt < 4; ++dt) {
          int r = dt * 32 + l31;
          bfrag vf = *(const bfrag*)&V_[r * 64 + ((c8 ^ (r & 7)) << 3)];
          o[dt] = __builtin_amdgcn_mfma_f32_32x32x16_bf16(vf, pf.f, o[dt],
                                                          0, 0, 0);
        }
        __builtin_amdgcn_s_setprio(0);
      }
  }
  // reduce l across the kk-halves (lane and lane^32 own complementary rows)
  float lrow = (ls[0] + ls[1]) + (ls[2] + ls[3]);
  lrow += __shfl_xor(lrow, 32);
  float inv = 1.f / lrow;
  unsigned short* Op = Ot + ((size_t)b * HW + q) * CCH + h * HD;
#pragma unroll
  for (int dt = 0; dt < 4; ++dt)
#pragma unroll
    for (int rg = 0; rg < 4; ++rg) {
      int d = dt * 32 + rg * 8 + half * 4;
      uint2 st;
      st.x = cvt_pk_bf16(o[dt][rg * 4 + 0] * inv, o[dt][rg * 4 + 1] * inv);
      st.y = cvt_pk_bf16(o[dt][rg * 4 + 2] * inv, o[dt][rg * 4 + 3] * inv);
      *(uint2*)&Op[d] = st;
    }
}

extern "C" void kernel_launch(void* const* d_in, const int* in_sizes, int n_in,
                              void* d_out, int out_size, void* d_ws,
                              size_t ws_size, hipStream_t stream) {
  const float* x = (const float*)d_in[0];
  const float* gamma = (const float*)d_in[1];
  const float* beta = (const float*)d_in[2];
  const float* wq = (const float*)d_in[3];
  const float* bq = (const float*)d_in[4];
  const float* wk = (const float*)d_in[5];
  const float* bk = (const float*)d_in[6];
  const float* wv = (const float*)d_in[7];
  const float* bv = (const float*)d_in[8];
  const float* wp = (const float*)d_in[9];
  const float* bp = (const float*)d_in[10];

  const size_t TS = (size_t)BATCH * HW * CCH;
  unsigned short* wB = (unsigned short*)d_ws;  // [4][512][512] bf16 (q,k,v,p)
  unsigned short* hn = wB + (size_t)4 * CCH * CCH;
  unsigned short* Qt = hn + TS;
  unsigned short* Kt = Qt + TS;
  unsigned short* Vc = Kt + TS;
  unsigned short* Ot = hn;  // reuse hn after QKV

  // 5 launches: gn+wcvt | QK(256^2 4-phase) | V | attn | P
  gnw_kernel<<<dim3(1536), 256, 0, stream>>>(x, gamma, beta, hn,
                                             wq, wk, wv, wp, wB);
  qk_kernel<<<dim3(4, 4, BATCH), 512, 0, stream>>>(hn, wB, bq, bk, Qt, Kt);
  mm_kernel<1><<<dim3(8, 4, BATCH), 256, 0, stream>>>(
      hn, wB + (size_t)2 * CCH * CCH, bv, nullptr, Vc, nullptr);
  attn_kernel<<<dim3(64, 8), 256, 0, stream>>>(Qt, Kt, Vc, Ot);
  mm_kernel<2><<<dim3(8, 4, BATCH), 256, 0, stream>>>(
      Ot, wB + (size_t)3 * CCH * CCH, bp, x, nullptr, (float*)d_out);
}